// Round 1
// baseline (1230.123 us; speedup 1.0000x reference)
//
#include <hip/hip_runtime.h>
#include <cstdint>

// ---- problem constants (B=8,T=4096 -> N=32768; EMB=1024; HID=2048; E=8; k=2) ----
#define NTOK   32768
#define EMB_D  1024
#define HID_H  2048
#define NEXP   8
#define CAP    5120               // int(1.25 * 32768 / 8)
#define MROWS  (NEXP * CAP)       // 40960 expert-buffer rows total

typedef __bf16 bf16_t;
typedef bf16_t bf16x8 __attribute__((ext_vector_type(8)));
typedef float  f32x4  __attribute__((ext_vector_type(4)));

typedef __attribute__((address_space(3))) void       lds_void_t;
typedef const __attribute__((address_space(1))) void g_void_t;

// global -> LDS direct copy, 16B per lane. LDS dest must be wave-uniform base + lane*16
// (our slot mapping satisfies this: slot = r*256 + tid, lds offset = slot*16B).
__device__ __forceinline__ void gload_lds16(const void* g, void* l) {
    __builtin_amdgcn_global_load_lds((g_void_t*)(uintptr_t)g,
                                     (lds_void_t*)(uint32_t)(uintptr_t)l, 16, 0, 0);
}

// =====================================================================
// Router: logits = x@wr + br ; z-loss partials ; softmax ; top-2 (ties -> lowest idx)
// one wave per token; wr staged in LDS as [e][d] (conflict-free b32 reads)
// =====================================================================
__global__ void router_kernel(const float* __restrict__ x, const float* __restrict__ wr,
                              const float* __restrict__ br, int2* __restrict__ top2,
                              float* __restrict__ zsum) {
    __shared__ float s_wr[NEXP * EMB_D];   // [e][d], 32 KB
    __shared__ float s_z[4];
    const int tid = threadIdx.x;           // 256
    for (int i = tid; i < NEXP * EMB_D; i += 256) {
        int d = i >> 3, e = i & 7;         // wr is [d][e] row-major
        s_wr[e * EMB_D + d] = wr[i];
    }
    __syncthreads();
    const int wid = tid >> 6, lane = tid & 63;
    const int t = blockIdx.x * 4 + wid;
    const float* xr = x + (size_t)t * EMB_D;

    float acc[NEXP];
#pragma unroll
    for (int e = 0; e < NEXP; e++) acc[e] = 0.f;
#pragma unroll
    for (int it = 0; it < EMB_D / 64; ++it) {
        float xv = xr[lane + 64 * it];
#pragma unroll
        for (int e = 0; e < NEXP; e++) acc[e] += xv * s_wr[e * EMB_D + lane + 64 * it];
    }
#pragma unroll
    for (int e = 0; e < NEXP; e++) {
        float v = acc[e];
#pragma unroll
        for (int off = 32; off > 0; off >>= 1) v += __shfl_xor(v, off);
        acc[e] = v;
    }
    if (lane == 0) {
        float lg[NEXP]; float zs = 0.f;
#pragma unroll
        for (int e = 0; e < NEXP; e++) { lg[e] = acc[e] + br[e]; zs += lg[e] * lg[e]; }
        s_z[wid] = zs;
        float mx = lg[0];
        for (int e = 1; e < NEXP; e++) mx = fmaxf(mx, lg[e]);
        float p[NEXP]; float se = 0.f;
        for (int e = 0; e < NEXP; e++) { p[e] = expf(lg[e] - mx); se += p[e]; }
        for (int e = 0; e < NEXP; e++) p[e] = p[e] / se;
        int i0 = 0; float b0 = p[0];
        for (int e = 1; e < NEXP; e++) if (p[e] > b0) { b0 = p[e]; i0 = e; }
        int i1 = -1; float b1v = -1.f;
        for (int e = 0; e < NEXP; e++) if (e != i0 && p[e] > b1v) { b1v = p[e]; i1 = e; }
        top2[t] = make_int2(i0, i1);
    }
    __syncthreads();
    if (tid == 0) unsafeAtomicAdd(zsum, s_z[0] + s_z[1] + s_z[2] + s_z[3]);
}

// =====================================================================
// Capacity scan: per expert (block), in token order: rank = running prefix of mask;
// keep first CAP; buf[e][pos] = token; pad with NTOK; usage[e] = kept count.
// =====================================================================
__global__ void scan_kernel(const int2* __restrict__ top2, int* __restrict__ buf,
                            int* __restrict__ usage) {
    const int e = blockIdx.x;
    __shared__ int wpre[16];
    __shared__ int s_tot;
    __shared__ int s_base;
    const int tid = threadIdx.x;   // 1024
    const int wid = tid >> 6, lane = tid & 63;
    if (tid == 0) s_base = 0;
    __syncthreads();
    for (int c0 = 0; c0 < NTOK; c0 += 1024) {
        const int t = c0 + tid;
        const int2 tp = top2[t];
        const bool m = (tp.x == e) || (tp.y == e);
        unsigned long long bal = __ballot(m);
        int lpre = __popcll(bal & ((1ull << lane) - 1ull));
        if (lane == 0) wpre[wid] = __popcll(bal);
        __syncthreads();
        if (tid == 0) {
            int a = 0;
            for (int w = 0; w < 16; w++) { int v = wpre[w]; wpre[w] = a; a += v; }
            s_tot = a;
        }
        __syncthreads();
        const int pos = s_base + wpre[wid] + lpre;
        if (m && pos < CAP) buf[e * CAP + pos] = t;
        __syncthreads();
        if (tid == 0) s_base += s_tot;
        __syncthreads();
    }
    const int cnt = s_base;
    const int used = cnt < CAP ? cnt : CAP;
    if (tid == 0) usage[e] = used;
    for (int p = used + tid; p < CAP; p += 1024) buf[e * CAP + p] = NTOK;
}

// =====================================================================
// Gather: Xg[row][d] = bf16(x[buf[row]][d])  (zero row for pad)
// =====================================================================
__global__ void gather_kernel(const float* __restrict__ x, const int* __restrict__ buf,
                              bf16_t* __restrict__ Xg) {
    const int row = blockIdx.x;
    const int t = buf[row];
    const int tid = threadIdx.x;   // 128, 8 elems each
    bf16x8 v;
    if (t < NTOK) {
        const float* xr = x + (size_t)t * EMB_D + tid * 8;
        const float4 a = *(const float4*)(xr);
        const float4 b = *(const float4*)(xr + 4);
        v[0] = (bf16_t)a.x; v[1] = (bf16_t)a.y; v[2] = (bf16_t)a.z; v[3] = (bf16_t)a.w;
        v[4] = (bf16_t)b.x; v[5] = (bf16_t)b.y; v[6] = (bf16_t)b.z; v[7] = (bf16_t)b.w;
    } else {
#pragma unroll
        for (int i = 0; i < 8; i++) v[i] = (bf16_t)0.f;
    }
    *(bf16x8*)(Xg + (size_t)row * EMB_D + tid * 8) = v;
}

// =====================================================================
// Transpose + convert: in[e][R][C] fp32 -> out[e][C][R] bf16 (GEMM B-operands
// need K-contiguous rows). 64x64 tiles via LDS.
// =====================================================================
__global__ void transpose_conv_kernel(const float* __restrict__ in, bf16_t* __restrict__ out,
                                      int R, int C) {
    __shared__ bf16_t tile[64][72];
    const int e = blockIdx.z;
    const int c0 = blockIdx.x * 64, r0 = blockIdx.y * 64;
    const float*  ip = in  + (size_t)e * R * C;
    bf16_t*       op = out + (size_t)e * R * C;
    const int tid = threadIdx.x;   // 256
    const int tr = tid >> 4;             // 0..15
    const int tc = (tid & 15) * 4;       // 0..60
#pragma unroll
    for (int rr = 0; rr < 64; rr += 16) {
        const float4 v = *(const float4*)(ip + (size_t)(r0 + tr + rr) * C + (c0 + tc));
        tile[tr + rr][tc + 0] = (bf16_t)v.x;
        tile[tr + rr][tc + 1] = (bf16_t)v.y;
        tile[tr + rr][tc + 2] = (bf16_t)v.z;
        tile[tr + rr][tc + 3] = (bf16_t)v.w;
    }
    __syncthreads();
    const int oc = tid >> 2;          // 0..63  (output row within tile = input col)
    const int og = (tid & 3) * 16;    // 0,16,32,48
    bf16x8 v0, v1;
#pragma unroll
    for (int i = 0; i < 8; i++) v0[i] = tile[og + i][oc];
#pragma unroll
    for (int i = 0; i < 8; i++) v1[i] = tile[og + 8 + i][oc];
    *(bf16x8*)(op + (size_t)(c0 + oc) * R + r0 + og)     = v0;
    *(bf16x8*)(op + (size_t)(c0 + oc) * R + r0 + og + 8) = v1;
}

// =====================================================================
// MFMA GEMM mainloop (m97-style): 128x128 tile, BK=32, 4 waves (2x2), each wave
// 64x64 via 4x4 array of 16x16x32 bf16 MFMAs. A[M][K], B[N][K] both K-contiguous.
// =====================================================================
__device__ __forceinline__ void mfma_mainloop(const bf16_t* __restrict__ Ap,
                                              const bf16_t* __restrict__ Bp,
                                              int K, bf16_t* ldsA, bf16_t* ldsB,
                                              f32x4 (&acc)[4][4]) {
    const int tid = threadIdx.x;
    const int wid = tid >> 6, lane = tid & 63;
    const int wm = wid >> 1, wn = wid & 1;
    const int quad = lane >> 4, l16 = lane & 15;
    const int s0 = tid, s1 = 256 + tid;
    const int row0 = s0 >> 2, ko0 = (s0 & 3) * 8;
    const int row1 = s1 >> 2, ko1 = (s1 & 3) * 8;

    for (int k0 = 0; k0 < K; k0 += 32) {
        __syncthreads();   // previous iteration's LDS reads done
        gload_lds16(Ap + (size_t)row0 * K + k0 + ko0, ldsA + s0 * 8);
        gload_lds16(Ap + (size_t)row1 * K + k0 + ko1, ldsA + s1 * 8);
        gload_lds16(Bp + (size_t)row0 * K + k0 + ko0, ldsB + s0 * 8);
        gload_lds16(Bp + (size_t)row1 * K + k0 + ko1, ldsB + s1 * 8);
        __builtin_amdgcn_s_waitcnt(0);   // drain this wave's global_load_lds
        __syncthreads();                 // all waves' tiles landed

        bf16x8 af[4], bfr[4];
#pragma unroll
        for (int i = 0; i < 4; i++) {
            af[i]  = *(const bf16x8*)(ldsA + (wm * 64 + i * 16 + l16) * 32 + quad * 8);
            bfr[i] = *(const bf16x8*)(ldsB + (wn * 64 + i * 16 + l16) * 32 + quad * 8);
        }
#pragma unroll
        for (int i = 0; i < 4; i++)
#pragma unroll
            for (int j = 0; j < 4; j++)
                acc[i][j] = __builtin_amdgcn_mfma_f32_16x16x32_bf16(af[i], bfr[j], acc[i][j], 0, 0, 0);
    }
}

// GEMM1: H[row][col] = gelu_exact(Xg @ w1t^T + b1), bf16 out. K=1024, N=2048.
__global__ void gemm1_kernel(const bf16_t* __restrict__ Xg, const bf16_t* __restrict__ w1t,
                             const float* __restrict__ b1, bf16_t* __restrict__ H) {
    __shared__ bf16_t ldsA[128 * 32];
    __shared__ bf16_t ldsB[128 * 32];
    const int bm = blockIdx.x, bn = blockIdx.y;
    const int e = bm / (CAP / 128);
    const bf16_t* Ap = Xg + (size_t)bm * 128 * EMB_D;
    const bf16_t* Bp = w1t + ((size_t)e * HID_H + bn * 128) * EMB_D;
    f32x4 acc[4][4];
    const f32x4 z4 = {0.f, 0.f, 0.f, 0.f};
#pragma unroll
    for (int i = 0; i < 4; i++)
#pragma unroll
        for (int j = 0; j < 4; j++) acc[i][j] = z4;

    mfma_mainloop(Ap, Bp, EMB_D, ldsA, ldsB, acc);

    const int tid = threadIdx.x;
    const int wid = tid >> 6, lane = tid & 63;
    const int wm = wid >> 1, wn = wid & 1;
    const int quad = lane >> 4, l16 = lane & 15;
#pragma unroll
    for (int j = 0; j < 4; j++) {
        const int col = bn * 128 + wn * 64 + j * 16 + l16;
        const float bias = b1[e * HID_H + col];
#pragma unroll
        for (int i = 0; i < 4; i++) {
            const int rowb = bm * 128 + wm * 64 + i * 16 + quad * 4;
#pragma unroll
            for (int r = 0; r < 4; r++) {
                const float v = acc[i][j][r] + bias;
                const float g = 0.5f * v * (1.f + erff(v * 0.7071067811865475f));
                H[(size_t)(rowb + r) * HID_H + col] = (bf16_t)g;
            }
        }
    }
}

// GEMM2: out[token] += H @ w2t^T + b2 (atomic scatter via buf; pad rows skipped).
// K=2048, N=1024.
__global__ void gemm2_kernel(const bf16_t* __restrict__ H, const bf16_t* __restrict__ w2t,
                             const float* __restrict__ b2, const int* __restrict__ buf,
                             float* __restrict__ out) {
    __shared__ bf16_t ldsA[128 * 32];
    __shared__ bf16_t ldsB[128 * 32];
    const int bm = blockIdx.x, bn = blockIdx.y;
    const int e = bm / (CAP / 128);
    const bf16_t* Ap = H + (size_t)bm * 128 * HID_H;
    const bf16_t* Bp = w2t + ((size_t)e * EMB_D + bn * 128) * HID_H;
    f32x4 acc[4][4];
    const f32x4 z4 = {0.f, 0.f, 0.f, 0.f};
#pragma unroll
    for (int i = 0; i < 4; i++)
#pragma unroll
        for (int j = 0; j < 4; j++) acc[i][j] = z4;

    mfma_mainloop(Ap, Bp, HID_H, ldsA, ldsB, acc);

    const int tid = threadIdx.x;
    const int wid = tid >> 6, lane = tid & 63;
    const int wm = wid >> 1, wn = wid & 1;
    const int quad = lane >> 4, l16 = lane & 15;
#pragma unroll
    for (int i = 0; i < 4; i++) {
        const int rowb = bm * 128 + wm * 64 + i * 16 + quad * 4;
#pragma unroll
        for (int r = 0; r < 4; r++) {
            const int t = buf[rowb + r];
            if (t < NTOK) {
#pragma unroll
                for (int j = 0; j < 4; j++) {
                    const int col = bn * 128 + wn * 64 + j * 16 + l16;
                    const float v = acc[i][j][r] + b2[e * EMB_D + col];
                    unsafeAtomicAdd(out + (size_t)t * EMB_D + col, v);
                }
            }
        }
    }
}

// =====================================================================
// Finalize: loss = E*sum(load^2) + 0.001*mean(logits^2); usage floats.
// =====================================================================
__global__ void finalize_kernel(const int* __restrict__ usage, const float* __restrict__ zsum,
                                float* __restrict__ out) {
    if (threadIdx.x == 0) {
        float u[NEXP], s = 0.f;
        for (int e = 0; e < NEXP; e++) { u[e] = (float)usage[e]; s += u[e]; }
        const float inv = 1.f / (s + 1e-6f);
        float bal = 0.f;
        for (int e = 0; e < NEXP; e++) { const float l = u[e] * inv; bal += l * l; }
        bal *= (float)NEXP;
        const float z = 0.001f * zsum[0] / (float)((size_t)NTOK * NEXP);
        out[(size_t)NTOK * EMB_D] = bal + z;
        for (int e = 0; e < NEXP; e++) out[(size_t)NTOK * EMB_D + 1 + e] = u[e];
    }
}

extern "C" void kernel_launch(void* const* d_in, const int* in_sizes, int n_in,
                              void* d_out, int out_size, void* d_ws, size_t ws_size,
                              hipStream_t stream) {
    (void)in_sizes; (void)n_in;
    const float* x  = (const float*)d_in[0];
    const float* wr = (const float*)d_in[1];
    const float* br = (const float*)d_in[2];
    const float* w1 = (const float*)d_in[3];
    const float* b1 = (const float*)d_in[4];
    const float* w2 = (const float*)d_in[5];
    const float* b2 = (const float*)d_in[6];
    float* out = (float*)d_out;

    uint8_t* ws = (uint8_t*)d_ws;
    size_t off = 0;
    auto carve = [&](size_t bytes) -> void* {
        off = (off + 255) & ~(size_t)255;
        void* p = ws + off;
        off += bytes;
        return p;
    };
    float*  zsum = (float*)carve(sizeof(float));
    int*    usage = (int*)carve(NEXP * sizeof(int));
    int2*   top2 = (int2*)carve((size_t)NTOK * sizeof(int2));
    int*    buf  = (int*)carve((size_t)MROWS * sizeof(int));
    bf16_t* Xg   = (bf16_t*)carve((size_t)MROWS * EMB_D * sizeof(bf16_t));
    bf16_t* w1t  = (bf16_t*)carve((size_t)NEXP * HID_H * EMB_D * sizeof(bf16_t));
    bf16_t* w2t  = (bf16_t*)carve((size_t)NEXP * EMB_D * HID_H * sizeof(bf16_t));
    bf16_t* H    = (bf16_t*)carve((size_t)MROWS * HID_H * sizeof(bf16_t));
    if (off > ws_size) return;   // workspace too small: fail loudly (output stays poisoned)

    hipMemsetAsync(d_out, 0, (size_t)out_size * sizeof(float), stream);
    hipMemsetAsync(zsum, 0, sizeof(float), stream);

    router_kernel<<<NTOK / 4, 256, 0, stream>>>(x, wr, br, top2, zsum);
    scan_kernel<<<NEXP, 1024, 0, stream>>>(top2, buf, usage);
    gather_kernel<<<MROWS, 128, 0, stream>>>(x, buf, Xg);
    transpose_conv_kernel<<<dim3(HID_H / 64, EMB_D / 64, NEXP), 256, 0, stream>>>(w1, w1t, EMB_D, HID_H);
    transpose_conv_kernel<<<dim3(EMB_D / 64, HID_H / 64, NEXP), 256, 0, stream>>>(w2, w2t, HID_H, EMB_D);
    gemm1_kernel<<<dim3(MROWS / 128, HID_H / 128), 256, 0, stream>>>(Xg, w1t, b1, H);
    gemm2_kernel<<<dim3(MROWS / 128, EMB_D / 128), 256, 0, stream>>>(H, w2t, b2, buf, out);
    finalize_kernel<<<1, 64, 0, stream>>>(usage, zsum, out);
}

// Round 2
// 969.386 us; speedup vs baseline: 1.2690x; 1.2690x over previous
//
#include <hip/hip_runtime.h>
#include <cstdint>

// ---- problem constants (B=8,T=4096 -> N=32768; EMB=1024; HID=2048; E=8; k=2) ----
#define NTOK   32768
#define EMB_D  1024
#define HID_H  2048
#define NEXP   8
#define CAP    5120               // int(1.25 * 32768 / 8)
#define MROWS  (NEXP * CAP)       // 40960 expert-buffer rows total
#define NCHUNK 32                 // token chunks for parallel scan (1024 tokens each)

typedef __bf16 bf16_t;
typedef bf16_t bf16x8 __attribute__((ext_vector_type(8)));
typedef float  f32x4  __attribute__((ext_vector_type(4)));

typedef __attribute__((address_space(3))) void       lds_void_t;
typedef const __attribute__((address_space(1))) void g_void_t;

__device__ __forceinline__ void gload_lds16(const void* g, void* l) {
    __builtin_amdgcn_global_load_lds((g_void_t*)(uintptr_t)g,
                                     (lds_void_t*)(uint32_t)(uintptr_t)l, 16, 0, 0);
}

// =====================================================================
// Router: logits = x@wr + br ; z-loss partials ; softmax ; top-2
// =====================================================================
__global__ void router_kernel(const float* __restrict__ x, const float* __restrict__ wr,
                              const float* __restrict__ br, int2* __restrict__ top2,
                              float* __restrict__ zsum) {
    __shared__ float s_wr[NEXP * EMB_D];   // [e][d], 32 KB
    __shared__ float s_z[4];
    const int tid = threadIdx.x;           // 256
    for (int i = tid; i < NEXP * EMB_D; i += 256) {
        int d = i >> 3, e = i & 7;         // wr is [d][e] row-major
        s_wr[e * EMB_D + d] = wr[i];
    }
    __syncthreads();
    const int wid = tid >> 6, lane = tid & 63;
    const int t = blockIdx.x * 4 + wid;
    const float* xr = x + (size_t)t * EMB_D;

    float acc[NEXP];
#pragma unroll
    for (int e = 0; e < NEXP; e++) acc[e] = 0.f;
#pragma unroll
    for (int it = 0; it < EMB_D / 64; ++it) {
        float xv = xr[lane + 64 * it];
#pragma unroll
        for (int e = 0; e < NEXP; e++) acc[e] += xv * s_wr[e * EMB_D + lane + 64 * it];
    }
#pragma unroll
    for (int e = 0; e < NEXP; e++) {
        float v = acc[e];
#pragma unroll
        for (int off = 32; off > 0; off >>= 1) v += __shfl_xor(v, off);
        acc[e] = v;
    }
    if (lane == 0) {
        float lg[NEXP]; float zs = 0.f;
#pragma unroll
        for (int e = 0; e < NEXP; e++) { lg[e] = acc[e] + br[e]; zs += lg[e] * lg[e]; }
        s_z[wid] = zs;
        float mx = lg[0];
        for (int e = 1; e < NEXP; e++) mx = fmaxf(mx, lg[e]);
        float p[NEXP]; float se = 0.f;
        for (int e = 0; e < NEXP; e++) { p[e] = expf(lg[e] - mx); se += p[e]; }
        for (int e = 0; e < NEXP; e++) p[e] = p[e] / se;
        int i0 = 0; float b0 = p[0];
        for (int e = 1; e < NEXP; e++) if (p[e] > b0) { b0 = p[e]; i0 = e; }
        int i1 = -1; float b1v = -1.f;
        for (int e = 0; e < NEXP; e++) if (e != i0 && p[e] > b1v) { b1v = p[e]; i1 = e; }
        top2[t] = make_int2(i0, i1);
    }
    __syncthreads();
    if (tid == 0) unsafeAtomicAdd(zsum, s_z[0] + s_z[1] + s_z[2] + s_z[3]);
}

// =====================================================================
// Parallel capacity scan: count -> prefix -> place (+inverse map) -> pad
// =====================================================================
__global__ void count_kernel(const int2* __restrict__ top2, int* __restrict__ counts) {
    const int chunk = blockIdx.x;          // 32 chunks x 1024 tokens
    const int tid = threadIdx.x;           // 1024
    const int wid = tid >> 6, lane = tid & 63;
    __shared__ int wcnt[NEXP][16];
    const int2 tp = top2[chunk * 1024 + tid];
#pragma unroll
    for (int e = 0; e < NEXP; e++) {
        const bool m = (tp.x == e) || (tp.y == e);
        unsigned long long bal = __ballot(m);
        if (lane == 0) wcnt[e][wid] = __popcll(bal);
    }
    __syncthreads();
    if (tid < NEXP) {
        int s = 0;
        for (int w = 0; w < 16; w++) s += wcnt[tid][w];
        counts[chunk * NEXP + tid] = s;
    }
}

__global__ void prefix_kernel(const int* __restrict__ counts, int* __restrict__ base,
                              int* __restrict__ usage) {
    const int e = threadIdx.x;
    if (e < NEXP) {
        int run = 0;
        for (int c = 0; c < NCHUNK; c++) {
            base[c * NEXP + e] = run;
            run += counts[c * NEXP + e];
        }
        usage[e] = run < CAP ? run : CAP;
    }
}

__global__ void place_kernel(const int2* __restrict__ top2, const int* __restrict__ base,
                             int* __restrict__ buf, int* __restrict__ inv) {
    const int chunk = blockIdx.x;
    const int tid = threadIdx.x;           // 1024
    const int wid = tid >> 6, lane = tid & 63;
    const int t = chunk * 1024 + tid;
    __shared__ int wpre[NEXP][16];
    const int2 tp = top2[t];
    int lpre[NEXP]; bool mm[NEXP];
#pragma unroll
    for (int e = 0; e < NEXP; e++) {
        mm[e] = (tp.x == e) || (tp.y == e);
        unsigned long long bal = __ballot(mm[e]);
        lpre[e] = __popcll(bal & ((1ull << lane) - 1ull));
        if (lane == 0) wpre[e][wid] = __popcll(bal);
    }
    __syncthreads();
    if (tid < NEXP) {
        int a = 0;
        for (int w = 0; w < 16; w++) { int v = wpre[tid][w]; wpre[tid][w] = a; a += v; }
    }
    __syncthreads();
#pragma unroll
    for (int e = 0; e < NEXP; e++) {
        if (mm[e]) {
            const int pos = base[chunk * NEXP + e] + wpre[e][wid] + lpre[e];
            const int slot = (tp.x == e) ? 0 : 1;
            if (pos < CAP) {
                const int row = e * CAP + pos;
                buf[row] = t;
                inv[t * 2 + slot] = row;
            } else {
                inv[t * 2 + slot] = -1;
            }
        }
    }
}

__global__ void pad_kernel(const int* __restrict__ usage, int* __restrict__ buf) {
    const int e = blockIdx.x;
    const int u = usage[e];
    for (int p = u + threadIdx.x; p < CAP; p += blockDim.x) buf[e * CAP + p] = NTOK;
}

// =====================================================================
// Gather: Xg[row][d] = bf16(x[buf[row]][d])  (zero row for pad)
// =====================================================================
__global__ void gather_kernel(const float* __restrict__ x, const int* __restrict__ buf,
                              bf16_t* __restrict__ Xg) {
    const int row = blockIdx.x;
    const int t = buf[row];
    const int tid = threadIdx.x;   // 128, 8 elems each
    bf16x8 v;
    if (t >= 0 && t < NTOK) {
        const float* xr = x + (size_t)t * EMB_D + tid * 8;
        const float4 a = *(const float4*)(xr);
        const float4 b = *(const float4*)(xr + 4);
        v[0] = (bf16_t)a.x; v[1] = (bf16_t)a.y; v[2] = (bf16_t)a.z; v[3] = (bf16_t)a.w;
        v[4] = (bf16_t)b.x; v[5] = (bf16_t)b.y; v[6] = (bf16_t)b.z; v[7] = (bf16_t)b.w;
    } else {
#pragma unroll
        for (int i = 0; i < 8; i++) v[i] = (bf16_t)0.f;
    }
    *(bf16x8*)(Xg + (size_t)row * EMB_D + tid * 8) = v;
}

// =====================================================================
// Transpose + convert: in[e][R][C] fp32 -> out[e][C][R] bf16
// =====================================================================
__global__ void transpose_conv_kernel(const float* __restrict__ in, bf16_t* __restrict__ out,
                                      int R, int C) {
    __shared__ bf16_t tile[64][72];
    const int e = blockIdx.z;
    const int c0 = blockIdx.x * 64, r0 = blockIdx.y * 64;
    const float*  ip = in  + (size_t)e * R * C;
    bf16_t*       op = out + (size_t)e * R * C;
    const int tid = threadIdx.x;   // 256
    const int tr = tid >> 4;
    const int tc = (tid & 15) * 4;
#pragma unroll
    for (int rr = 0; rr < 64; rr += 16) {
        const float4 v = *(const float4*)(ip + (size_t)(r0 + tr + rr) * C + (c0 + tc));
        tile[tr + rr][tc + 0] = (bf16_t)v.x;
        tile[tr + rr][tc + 1] = (bf16_t)v.y;
        tile[tr + rr][tc + 2] = (bf16_t)v.z;
        tile[tr + rr][tc + 3] = (bf16_t)v.w;
    }
    __syncthreads();
    const int oc = tid >> 2;
    const int og = (tid & 3) * 16;
    bf16x8 v0, v1;
#pragma unroll
    for (int i = 0; i < 8; i++) v0[i] = tile[og + i][oc];
#pragma unroll
    for (int i = 0; i < 8; i++) v1[i] = tile[og + 8 + i][oc];
    *(bf16x8*)(op + (size_t)(c0 + oc) * R + r0 + og)     = v0;
    *(bf16x8*)(op + (size_t)(c0 + oc) * R + r0 + og + 8) = v1;
}

// =====================================================================
// MFMA GEMM mainloop (m97-style): 128x128 tile, BK=32, 4 waves (2x2)
// =====================================================================
__device__ __forceinline__ void mfma_mainloop(const bf16_t* __restrict__ Ap,
                                              const bf16_t* __restrict__ Bp,
                                              int K, bf16_t* ldsA, bf16_t* ldsB,
                                              f32x4 (&acc)[4][4]) {
    const int tid = threadIdx.x;
    const int wid = tid >> 6, lane = tid & 63;
    const int wm = wid >> 1, wn = wid & 1;
    const int quad = lane >> 4, l16 = lane & 15;
    const int s0 = tid, s1 = 256 + tid;
    const int row0 = s0 >> 2, ko0 = (s0 & 3) * 8;
    const int row1 = s1 >> 2, ko1 = (s1 & 3) * 8;

    for (int k0 = 0; k0 < K; k0 += 32) {
        __syncthreads();
        gload_lds16(Ap + (size_t)row0 * K + k0 + ko0, ldsA + s0 * 8);
        gload_lds16(Ap + (size_t)row1 * K + k0 + ko1, ldsA + s1 * 8);
        gload_lds16(Bp + (size_t)row0 * K + k0 + ko0, ldsB + s0 * 8);
        gload_lds16(Bp + (size_t)row1 * K + k0 + ko1, ldsB + s1 * 8);
        __builtin_amdgcn_s_waitcnt(0);
        __syncthreads();

        bf16x8 af[4], bfr[4];
#pragma unroll
        for (int i = 0; i < 4; i++) {
            af[i]  = *(const bf16x8*)(ldsA + (wm * 64 + i * 16 + l16) * 32 + quad * 8);
            bfr[i] = *(const bf16x8*)(ldsB + (wn * 64 + i * 16 + l16) * 32 + quad * 8);
        }
#pragma unroll
        for (int i = 0; i < 4; i++)
#pragma unroll
            for (int j = 0; j < 4; j++)
                acc[i][j] = __builtin_amdgcn_mfma_f32_16x16x32_bf16(af[i], bfr[j], acc[i][j], 0, 0, 0);
    }
}

// GEMM1: H = gelu_exact(Xg @ w1t^T + b1), bf16 out. (bn fast-varying for A-reuse)
__global__ void gemm1_kernel(const bf16_t* __restrict__ Xg, const bf16_t* __restrict__ w1t,
                             const float* __restrict__ b1, bf16_t* __restrict__ H) {
    __shared__ bf16_t ldsA[128 * 32];
    __shared__ bf16_t ldsB[128 * 32];
    const int bn = blockIdx.x, bm = blockIdx.y;
    const int e = bm / (CAP / 128);
    const bf16_t* Ap = Xg + (size_t)bm * 128 * EMB_D;
    const bf16_t* Bp = w1t + ((size_t)e * HID_H + bn * 128) * EMB_D;
    f32x4 acc[4][4];
    const f32x4 z4 = {0.f, 0.f, 0.f, 0.f};
#pragma unroll
    for (int i = 0; i < 4; i++)
#pragma unroll
        for (int j = 0; j < 4; j++) acc[i][j] = z4;

    mfma_mainloop(Ap, Bp, EMB_D, ldsA, ldsB, acc);

    const int tid = threadIdx.x;
    const int wid = tid >> 6, lane = tid & 63;
    const int wm = wid >> 1, wn = wid & 1;
    const int quad = lane >> 4, l16 = lane & 15;
#pragma unroll
    for (int j = 0; j < 4; j++) {
        const int col = bn * 128 + wn * 64 + j * 16 + l16;
        const float bias = b1[e * HID_H + col];
#pragma unroll
        for (int i = 0; i < 4; i++) {
            const int rowb = bm * 128 + wm * 64 + i * 16 + quad * 4;
#pragma unroll
            for (int r = 0; r < 4; r++) {
                const float v = acc[i][j][r] + bias;
                const float g = 0.5f * v * (1.f + erff(v * 0.7071067811865475f));
                H[(size_t)(rowb + r) * HID_H + col] = (bf16_t)g;
            }
        }
    }
}

// GEMM2: Yg = H @ w2t^T (bf16, dense; bias added in combine). bn fast-varying.
__global__ void gemm2_kernel(const bf16_t* __restrict__ H, const bf16_t* __restrict__ w2t,
                             bf16_t* __restrict__ Yg) {
    __shared__ bf16_t ldsA[128 * 32];
    __shared__ bf16_t ldsB[128 * 32];
    const int bn = blockIdx.x, bm = blockIdx.y;
    const int e = bm / (CAP / 128);
    const bf16_t* Ap = H + (size_t)bm * 128 * HID_H;
    const bf16_t* Bp = w2t + ((size_t)e * EMB_D + bn * 128) * HID_H;
    f32x4 acc[4][4];
    const f32x4 z4 = {0.f, 0.f, 0.f, 0.f};
#pragma unroll
    for (int i = 0; i < 4; i++)
#pragma unroll
        for (int j = 0; j < 4; j++) acc[i][j] = z4;

    mfma_mainloop(Ap, Bp, HID_H, ldsA, ldsB, acc);

    const int tid = threadIdx.x;
    const int wid = tid >> 6, lane = tid & 63;
    const int wm = wid >> 1, wn = wid & 1;
    const int quad = lane >> 4, l16 = lane & 15;
#pragma unroll
    for (int j = 0; j < 4; j++) {
        const int col = bn * 128 + wn * 64 + j * 16 + l16;
#pragma unroll
        for (int i = 0; i < 4; i++) {
            const int rowb = bm * 128 + wm * 64 + i * 16 + quad * 4;
#pragma unroll
            for (int r = 0; r < 4; r++)
                Yg[(size_t)(rowb + r) * EMB_D + col] = (bf16_t)acc[i][j][r];
        }
    }
}

// =====================================================================
// Combine: out[t] = sum over kept slots (Yg[row] + b2[expert]) ; 0 if dropped
// =====================================================================
__global__ void combine_kernel(const bf16_t* __restrict__ Yg, const float* __restrict__ b2,
                               const int* __restrict__ inv, float* __restrict__ out) {
    const int t = blockIdx.x;
    const int tid = threadIdx.x;   // 128, 8 floats each
    const int d = tid * 8;
    const int r0 = inv[t * 2], r1 = inv[t * 2 + 1];
    float acc[8];
#pragma unroll
    for (int i = 0; i < 8; i++) acc[i] = 0.f;
    if (r0 >= 0) {
        const int e = r0 / CAP;
        const bf16x8 v = *(const bf16x8*)(Yg + (size_t)r0 * EMB_D + d);
        const float* bp = b2 + e * EMB_D + d;
#pragma unroll
        for (int i = 0; i < 8; i++) acc[i] += (float)v[i] + bp[i];
    }
    if (r1 >= 0) {
        const int e = r1 / CAP;
        const bf16x8 v = *(const bf16x8*)(Yg + (size_t)r1 * EMB_D + d);
        const float* bp = b2 + e * EMB_D + d;
#pragma unroll
        for (int i = 0; i < 8; i++) acc[i] += (float)v[i] + bp[i];
    }
    float4 o0 = {acc[0], acc[1], acc[2], acc[3]};
    float4 o1 = {acc[4], acc[5], acc[6], acc[7]};
    *(float4*)(out + (size_t)t * EMB_D + d)     = o0;
    *(float4*)(out + (size_t)t * EMB_D + d + 4) = o1;
}

// =====================================================================
// Finalize: loss = E*sum(load^2) + 0.001*mean(logits^2); usage floats.
// =====================================================================
__global__ void finalize_kernel(const int* __restrict__ usage, const float* __restrict__ zsum,
                                float* __restrict__ out) {
    if (threadIdx.x == 0) {
        float u[NEXP], s = 0.f;
        for (int e = 0; e < NEXP; e++) { u[e] = (float)usage[e]; s += u[e]; }
        const float inv = 1.f / (s + 1e-6f);
        float bal = 0.f;
        for (int e = 0; e < NEXP; e++) { const float l = u[e] * inv; bal += l * l; }
        bal *= (float)NEXP;
        const float z = 0.001f * zsum[0] / (float)((size_t)NTOK * NEXP);
        out[(size_t)NTOK * EMB_D] = bal + z;
        for (int e = 0; e < NEXP; e++) out[(size_t)NTOK * EMB_D + 1 + e] = u[e];
    }
}

extern "C" void kernel_launch(void* const* d_in, const int* in_sizes, int n_in,
                              void* d_out, int out_size, void* d_ws, size_t ws_size,
                              hipStream_t stream) {
    (void)in_sizes; (void)n_in; (void)out_size;
    const float* x  = (const float*)d_in[0];
    const float* wr = (const float*)d_in[1];
    const float* br = (const float*)d_in[2];
    const float* w1 = (const float*)d_in[3];
    const float* b1 = (const float*)d_in[4];
    const float* w2 = (const float*)d_in[5];
    const float* b2 = (const float*)d_in[6];
    float* out = (float*)d_out;

    uint8_t* ws = (uint8_t*)d_ws;
    size_t off = 0;
    auto carve = [&](size_t bytes) -> void* {
        off = (off + 255) & ~(size_t)255;
        void* p = ws + off;
        off += bytes;
        return p;
    };
    float*  zsum  = (float*)carve(sizeof(float));
    int*    usage = (int*)carve(NEXP * sizeof(int));
    int*    counts = (int*)carve((size_t)NCHUNK * NEXP * sizeof(int));
    int*    base   = (int*)carve((size_t)NCHUNK * NEXP * sizeof(int));
    int2*   top2 = (int2*)carve((size_t)NTOK * sizeof(int2));
    int*    buf  = (int*)carve((size_t)MROWS * sizeof(int));
    int*    inv  = (int*)carve((size_t)NTOK * 2 * sizeof(int));
    bf16_t* Xg   = (bf16_t*)carve((size_t)MROWS * EMB_D * sizeof(bf16_t));
    bf16_t* w1t  = (bf16_t*)carve((size_t)NEXP * HID_H * EMB_D * sizeof(bf16_t));
    bf16_t* w2t  = (bf16_t*)carve((size_t)NEXP * EMB_D * HID_H * sizeof(bf16_t));
    bf16_t* H    = (bf16_t*)carve((size_t)MROWS * HID_H * sizeof(bf16_t));
    bf16_t* Yg   = Xg;   // Xg is dead after gemm1 -> reuse for gemm2 output
    if (off > ws_size) return;   // workspace too small: fail loudly

    hipMemsetAsync(zsum, 0, sizeof(float), stream);

    router_kernel<<<NTOK / 4, 256, 0, stream>>>(x, wr, br, top2, zsum);
    count_kernel<<<NCHUNK, 1024, 0, stream>>>(top2, counts);
    prefix_kernel<<<1, 64, 0, stream>>>(counts, base, usage);
    place_kernel<<<NCHUNK, 1024, 0, stream>>>(top2, base, buf, inv);
    pad_kernel<<<NEXP, 256, 0, stream>>>(usage, buf);
    gather_kernel<<<MROWS, 128, 0, stream>>>(x, buf, Xg);
    transpose_conv_kernel<<<dim3(HID_H / 64, EMB_D / 64, NEXP), 256, 0, stream>>>(w1, w1t, EMB_D, HID_H);
    transpose_conv_kernel<<<dim3(EMB_D / 64, HID_H / 64, NEXP), 256, 0, stream>>>(w2, w2t, HID_H, EMB_D);
    gemm1_kernel<<<dim3(HID_H / 128, MROWS / 128), 256, 0, stream>>>(Xg, w1t, b1, H);
    gemm2_kernel<<<dim3(EMB_D / 128, MROWS / 128), 256, 0, stream>>>(H, w2t, Yg);
    combine_kernel<<<NTOK, 128, 0, stream>>>(Yg, b2, inv, out);
    finalize_kernel<<<1, 64, 0, stream>>>(usage, zsum, out);
}